// Round 18
// baseline (206.613 us; speedup 1.0000x reference)
//
#include <hip/hip_runtime.h>

// PMField R24: 1024-thread blocks — force 16 waves/CU with ONE block/CU.
//  - R23 (139us best): 2x512-thr blocks did NOT co-reside (occ 22%, not 50).
//    But dur improved + VALUBusy 52->56: latency-bound model strengthened.
//    VALU-issue floor = 0.56*139 ~= 78us -> big headroom if waves arrive.
//  - R24: grid 256 = exactly 1 block/CU, 16 waves/block, LDS 64KB single
//    copy -> no second-block placement question; all work co-resident.
//    __launch_bounds__(1024,1) -> VGPR cap 512/4=128, body 80 -> clean fit
//    (every past spill was body>cap).
//  - Tripwires: VGPR clamp or WRITE>>33MB => void, revert R23.
//  - Body byte-identical to R22/R23 except staging (2 iters/thread) and
//    pbase: sA+sG LDS staging, frag-dual register packing, permuted-dim z
//    layout, pk-f32 elementwise, acc-init fold, r2=fmax(S,EPS), v_perm
//    packs, f32 cn2/mu, chunk unroll 2, split accumulators.
// Layouts (HW-verified): C/D col=lane&15,row=q*4+r; A[m=lane&15][k=q*8+j];
// B[k=8q+j][n=lane&15]. z reg (Mt,q,r) holds phys dim 32(Mt>>1)+8q+4(Mt&1)+r;
// center S-slot (c,Mt,q,r) == G k-slot 8q+4(Mt&1)+r of block Kt=Mt>>1.

#define STEPS 8
#define DTB   0.15f
#define EPSF  1e-4f

typedef short bf16x8 __attribute__((ext_vector_type(8)));
typedef float f32x4  __attribute__((ext_vector_type(4)));
typedef float f32x2  __attribute__((ext_vector_type(2)));
union FragU { int4 i; bf16x8 h; };

__device__ __forceinline__ f32x2 max2(f32x2 a, f32x2 b) {
    return __builtin_elementwise_max(a, b);
}
__device__ __forceinline__ f32x2 min2(f32x2 a, f32x2 b) {
    return __builtin_elementwise_min(a, b);
}

// byte-select pack: r = [lo.b2, lo.b3, hi.b2, hi.b3]  (one v_perm_b32)
__device__ __forceinline__ unsigned bfpt(float lo, float hi) { // trunc pack
    return __builtin_amdgcn_perm(__float_as_uint(hi), __float_as_uint(lo),
                                 0x07060302u);
}
__device__ __forceinline__ unsigned bfp(float lo, float hi) {  // round pack
    return __builtin_amdgcn_perm(__float_as_uint(hi) + 0x8000u,
                                 __float_as_uint(lo) + 0x8000u, 0x07060302u);
}

// d_ws layout:
//   int4 [0,    2048)  S-planes: ((c*4+Mt)*2+h)*64 + lane = bf16x8 of -2C[center][dims]
//   int4 [2048, 4096)  G-planes: ((Mt*4+c)*2+h)*64 + lane; row m16 -> perm dim
//                      D(Mt,m16); k-axis -> permuted centers cen(k)
//   f32  ws[16384..16640)  cn2[256]   (S-slot order: 64c+16Mt+4q+r)
//   f32  ws[16640..16896)  mu[256]
__global__ void pm_prep(const float* __restrict__ centers,
                        const float* __restrict__ mus,
                        unsigned* __restrict__ ws) {
    const int gtid = blockIdx.x * 256 + threadIdx.x;
    if (gtid < 2048) {                       // S-plane frags
        const int c = gtid >> 9, Mt = (gtid >> 7) & 3, h = (gtid >> 6) & 1;
        const int L = gtid & 63, m16 = L & 15, q = L >> 4;
        const float* row = centers + (size_t)(64 * c + 16 * Mt + m16) * 64 + 32 * h + 8 * q;
        uint4 u;
        u.x = bfp(-2.f * row[0], -2.f * row[1]);
        u.y = bfp(-2.f * row[2], -2.f * row[3]);
        u.z = bfp(-2.f * row[4], -2.f * row[5]);
        u.w = bfp(-2.f * row[6], -2.f * row[7]);
        ((uint4*)ws)[gtid] = u;
    } else if (gtid < 4096) {                // G-plane frags (permuted axes)
        const int i = gtid - 2048;
        const int Mt = i >> 9, c = (i >> 7) & 3, h = (i >> 6) & 1;
        const int L = i & 63, m16 = L & 15, q = L >> 4;
        const int dim = 32 * (Mt >> 1) + 8 * (m16 >> 2) + 4 * (Mt & 1) + (m16 & 3);
        const float* b0 = centers + (size_t)(64 * c + 32 * h + 4 * q) * 64 + dim;
        const float* b1 = b0 + 16 * 64;   // j=4..7 block (+16 centers)
        uint4 u;
        u.x = bfp(b0[0],   b0[64]);
        u.y = bfp(b0[128], b0[192]);
        u.z = bfp(b1[0],   b1[64]);
        u.w = bfp(b1[128], b1[192]);
        ((uint4*)ws)[gtid] = u;
    } else if (gtid < 4352) {                // cn2 / mu as f32 (S-slot order)
        const int t = gtid - 4096;
        const float* r = centers + (size_t)t * 64;
        float a0 = 0.f, a1 = 0.f, a2 = 0.f, a3 = 0.f;
#pragma unroll
        for (int d = 0; d < 64; d += 4) {
            a0 = fmaf(r[d],     r[d],     a0);
            a1 = fmaf(r[d + 1], r[d + 1], a1);
            a2 = fmaf(r[d + 2], r[d + 2], a2);
            a3 = fmaf(r[d + 3], r[d + 3], a3);
        }
        float c2 = (a0 + a1) + (a2 + a3);
        ((float*)ws)[16384 + t] = c2;
        ((float*)ws)[16640 + t] = mus[t];
    }
}

__global__ __launch_bounds__(1024, 1)
void pm_main(const float* __restrict__ z_in,
             const unsigned* __restrict__ ws,
             float* __restrict__ z_out) {
    __shared__ int4 sA[2048];          // 32 KB: S-plane frags, block-shared
    __shared__ int4 sG[2048];          // 32 KB: G-plane frags, block-shared

    const int4* wsA = (const int4*)ws;
    const int4* wsG = wsA + 2048;
    const float* wsC  = (const float*)ws + 16384;
    const float* wsMu = (const float*)ws + 16640;

    const int tid  = threadIdx.x;
    const int lane = tid & 63;
    const int w    = tid >> 6;         // wave 0..15
    const int m16  = lane & 15;
    const int q    = lane >> 4;

    // copy S+G planes to LDS (lane-linear, coalesced, conflict-free)
#pragma unroll
    for (int i = 0; i < 2; ++i) sA[i * 1024 + tid] = wsA[i * 1024 + tid];
#pragma unroll
    for (int i = 0; i < 2; ++i) sG[i * 1024 + tid] = wsG[i * 1024 + tid];
    __syncthreads();

    const int pbase = blockIdx.x * 512 + w * 32;   // 512 particles/block, 32/wave

    // z state, permuted-dim layout: register (Mt,Nt,r) holds physical dim
    // 32(Mt>>1) + 8q + 4(Mt&1) + r for particle m16+16Nt (contig f32x4 load)
    f32x4 z[4][2];
#pragma unroll
    for (int Mt = 0; Mt < 4; ++Mt)
#pragma unroll
        for (int Nt = 0; Nt < 2; ++Nt)
            z[Mt][Nt] = *(const f32x4*)(z_in + (size_t)(pbase + m16 + 16 * Nt) * 64
                                        + 32 * (Mt >> 1) + 8 * q + 4 * (Mt & 1));

#pragma unroll 1
    for (int s = 0; s < STEPS; ++s) {
        // zz per particle (pk pairs + butterfly over q groups; perm-invariant)
        float zzp[2];
#pragma unroll
        for (int Nt = 0; Nt < 2; ++Nt) {
            f32x2 a2 = (f32x2){0.f, 0.f};
#pragma unroll
            for (int Mt = 0; Mt < 4; ++Mt) {
                f32x2 lo = (f32x2){z[Mt][Nt][0], z[Mt][Nt][1]};
                f32x2 hi = (f32x2){z[Mt][Nt][2], z[Mt][Nt][3]};
                a2 += lo * lo;
                a2 += hi * hi;
            }
            float a = a2.x + a2.y;
            a += __shfl_xor(a, 16, 64);
            a += __shfl_xor(a, 32, 64);
            zzp[Nt] = a;
        }

        // z -> B-frags: pure register pack (no LDS)
        FragU zf[2][2];
#pragma unroll
        for (int Kt = 0; Kt < 2; ++Kt)
#pragma unroll
            for (int Nt = 0; Nt < 2; ++Nt) {
                zf[Kt][Nt].i.x = (int)bfp(z[2 * Kt][Nt][0],     z[2 * Kt][Nt][1]);
                zf[Kt][Nt].i.y = (int)bfp(z[2 * Kt][Nt][2],     z[2 * Kt][Nt][3]);
                zf[Kt][Nt].i.z = (int)bfp(z[2 * Kt + 1][Nt][0], z[2 * Kt + 1][Nt][1]);
                zf[Kt][Nt].i.w = (int)bfp(z[2 * Kt + 1][Nt][2], z[2 * Kt + 1][Nt][3]);
            }

        f32x4 g[4][2];
#pragma unroll
        for (int Mt = 0; Mt < 4; ++Mt)
#pragma unroll
            for (int Nt = 0; Nt < 2; ++Nt) g[Mt][Nt] = (f32x4){0.f, 0.f, 0.f, 0.f};
        f32x2 nacc2a[2] = {(f32x2){0.f, 0.f}, (f32x2){0.f, 0.f}};
        f32x2 nacc2b[2] = {(f32x2){0.f, 0.f}, (f32x2){0.f, 0.f}};
        f32x2 swp2a[2]  = {(f32x2){0.f, 0.f}, (f32x2){0.f, 0.f}};
        f32x2 swp2b[2]  = {(f32x2){0.f, 0.f}, (f32x2){0.f, 0.f}};

#pragma unroll 2
        for (int c = 0; c < 4; ++c) {          // 4 chunks x 64 centers
            // S-phase, fused per Mt; w B-frags (wfB) built in-register
            FragU wfB[2][2];
            const f32x2 eps2 = (f32x2){EPSF, EPSF};
#pragma unroll
            for (int Mt = 0; Mt < 4; ++Mt) {
                FragU a0, a1;
                a0.i = sA[((c * 4 + Mt) * 2 + 0) * 64 + lane];
                a1.i = sA[((c * 4 + Mt) * 2 + 1) * 64 + lane];
                const float4 cn4 = *(const float4*)(wsC  + 64 * c + 16 * Mt + 4 * q);
                const float4 mu4 = *(const float4*)(wsMu + 64 * c + 16 * Mt + 4 * q);
                const f32x2 cnlo = (f32x2){cn4.x, cn4.y}, cnhi = (f32x2){cn4.z, cn4.w};
                const f32x2 mulo = (f32x2){mu4.x, mu4.y}, muhi = (f32x2){mu4.z, mu4.w};
                f32x4 S[2];
#pragma unroll
                for (int Nt = 0; Nt < 2; ++Nt) {
                    const f32x2 zz2 = (f32x2){zzp[Nt], zzp[Nt]};
                    const f32x2 i0 = zz2 + cnlo, i1 = zz2 + cnhi;   // pk_add
                    f32x4 acc = (f32x4){i0.x, i0.y, i1.x, i1.y};
                    acc = __builtin_amdgcn_mfma_f32_16x16x32_bf16(a0.h, zf[0][Nt].h, acc, 0, 0, 0);
                    acc = __builtin_amdgcn_mfma_f32_16x16x32_bf16(a1.h, zf[1][Nt].h, acc, 0, 0, 0);
                    S[Nt] = acc;   // S = zz + |c|^2 - 2 z.c
                }

#pragma unroll
                for (int Nt = 0; Nt < 2; ++Nt) {
                    // packed elementwise: pairs (r0,r1) and (r2,r3)
                    f32x2 s0 = (f32x2){S[Nt][0], S[Nt][1]};
                    f32x2 s1 = (f32x2){S[Nt][2], S[Nt][3]};
                    f32x2 r20 = max2(s0, eps2);                 // == max(.,0)+eps here
                    f32x2 r21 = max2(s1, eps2);
                    f32x2 rin0, rin1;
                    rin0.x = __builtin_amdgcn_rsqf(r20.x);
                    rin0.y = __builtin_amdgcn_rsqf(r20.y);
                    rin1.x = __builtin_amdgcn_rsqf(r21.x);
                    rin1.y = __builtin_amdgcn_rsqf(r21.y);
                    f32x2 mur0 = mulo * rin0, mur1 = muhi * rin1;   // pk_mul
                    nacc2a[Nt] += mur0;                             // split chains (ILP)
                    nacc2b[Nt] += mur1;
                    f32x2 q0 = rin0 * rin0, q1 = rin1 * rin1;       // pk_mul
                    f32x2 wv0 = mur0 * q0,  wv1 = mur1 * q1;        // mu / r^3
                    swp2a[Nt] += wv0;                               // split chains (ILP)
                    swp2b[Nt] += wv1;
                    // w -> B-frag slot k=8q+4(Mt&1)+r of block Kt=Mt>>1
                    if ((Mt & 1) == 0) {
                        wfB[Mt >> 1][Nt].i.x = (int)bfpt(wv0.x, wv0.y);
                        wfB[Mt >> 1][Nt].i.y = (int)bfpt(wv1.x, wv1.y);
                    } else {
                        wfB[Mt >> 1][Nt].i.z = (int)bfpt(wv0.x, wv0.y);
                        wfB[Mt >> 1][Nt].i.w = (int)bfpt(wv1.x, wv1.y);
                    }
                }
            }

            // G-phase: ga frags from LDS (lane-linear, conflict-free);
            // wfB already in registers
#pragma unroll
            for (int Mt = 0; Mt < 4; ++Mt) {
                FragU ga0, ga1;
                ga0.i = sG[((Mt * 4 + c) * 2 + 0) * 64 + lane];
                ga1.i = sG[((Mt * 4 + c) * 2 + 1) * 64 + lane];
#pragma unroll
                for (int Nt = 0; Nt < 2; ++Nt) {
                    g[Mt][Nt] = __builtin_amdgcn_mfma_f32_16x16x32_bf16(ga0.h, wfB[0][Nt].h, g[Mt][Nt], 0, 0, 0);
                    g[Mt][Nt] = __builtin_amdgcn_mfma_f32_16x16x32_bf16(ga1.h, wfB[1][Nt].h, g[Mt][Nt], 0, 0, 0);
                }
            }
        }

        // reduce n, sw across q groups; packed z update
        float tco[2], swf[2];
#pragma unroll
        for (int Nt = 0; Nt < 2; ++Nt) {
            float a = (nacc2a[Nt].x + nacc2a[Nt].y) + (nacc2b[Nt].x + nacc2b[Nt].y);
            a += __shfl_xor(a, 16, 64);
            a += __shfl_xor(a, 32, 64);
            float b = (swp2a[Nt].x + swp2a[Nt].y) + (swp2b[Nt].x + swp2b[Nt].y);
            b += __shfl_xor(b, 16, 64);
            b += __shfl_xor(b, 32, 64);
            tco[Nt] = DTB * __builtin_amdgcn_rcpf(1.f + a);
            swf[Nt] = b;
        }
        const f32x2 lo2 = (f32x2){-3.f, -3.f}, hi2 = (f32x2){3.f, 3.f};
#pragma unroll
        for (int Mt = 0; Mt < 4; ++Mt)
#pragma unroll
            for (int Nt = 0; Nt < 2; ++Nt) {
                const f32x2 sw2 = (f32x2){swf[Nt], swf[Nt]};
                const f32x2 tc2 = (f32x2){tco[Nt], tco[Nt]};
#pragma unroll
                for (int p = 0; p < 2; ++p) {
                    f32x2 zp = (f32x2){z[Mt][Nt][2 * p], z[Mt][Nt][2 * p + 1]};
                    f32x2 gp = (f32x2){g[Mt][Nt][2 * p], g[Mt][Nt][2 * p + 1]};
                    f32x2 gd = gp - sw2 * zp;          // pk_fma
                    f32x2 zn = zp + tc2 * gd;          // pk_fma
                    zn = min2(max2(zn, lo2), hi2);     // pk_max + pk_min
                    z[Mt][Nt][2 * p]     = zn.x;
                    z[Mt][Nt][2 * p + 1] = zn.y;
                }
            }
    }

    // store: same permuted-dim contiguous f32x4 segments as the load
#pragma unroll
    for (int Mt = 0; Mt < 4; ++Mt)
#pragma unroll
        for (int Nt = 0; Nt < 2; ++Nt)
            *(f32x4*)(z_out + (size_t)(pbase + m16 + 16 * Nt) * 64
                      + 32 * (Mt >> 1) + 8 * q + 4 * (Mt & 1)) = z[Mt][Nt];
}

extern "C" void kernel_launch(void* const* d_in, const int* in_sizes, int n_in,
                              void* d_out, int out_size, void* d_ws, size_t ws_size,
                              hipStream_t stream) {
    const float* z       = (const float*)d_in[0];
    const float* centers = (const float*)d_in[1];
    const float* mus     = (const float*)d_in[2];
    float* out           = (float*)d_out;
    unsigned* ws         = (unsigned*)d_ws;

    pm_prep<<<dim3(17), dim3(256), 0, stream>>>(centers, mus, ws);
    // 131072 particles / 512 per block (16 waves x 32) = 256 blocks =
    // exactly 1 block/CU: 16 waves/CU forced, LDS 64KB single copy, no tail
    pm_main<<<dim3(256), dim3(1024), 0, stream>>>(z, ws, out);
}

// Round 19
// 205.442 us; speedup vs baseline: 1.0057x; 1.0057x over previous
//
#include <hip/hip_runtime.h>

// PMField R25: 512-thr blocks + 32KB LDS (sG only) — make 16 waves/CU real.
//  - R24 void: (1024,1) clamped VGPR to 64 -> spill (WRITE 156MB), 152us.
//    BUT occ hit 33% -> no hard residency pin; register cost killed it.
//  - R23 (138.5us best): 2x64KB blocks didn't co-reside (occ 22%). Fix:
//    halve per-block LDS to 32KB -> 2x32KB=64KB trivially resident.
//  - Which 32KB: keep sG (ga) in LDS -- the PROVEN win (R19 149 -> R20 143.5
//    was ga L1->LDS; G-phase consumes ga at the end of the serial chunk
//    chain where short LDS latency matters). sA back to global: S-phase
//    loads sit at the chunk START where unroll-2 prefetch across the
//    back-edge already covers L1/L2 latency (proven R19).
//  - (512,2) launch bounds: the proven-safe point at 512 thr (R23, VGPR 80).
//  - Tripwires: VGPR>=128-clamp or WRITE>>33MB => void, revert R23.
//  - Body otherwise identical to R23: frag-dual register packing, permuted-
//    dim z layout, pk-f32 elementwise, acc-init fold, r2=fmax(S,EPS),
//    v_perm packs, f32 cn2/mu, chunk unroll 2, split accumulators.
// Layouts (HW-verified): C/D col=lane&15,row=q*4+r; A[m=lane&15][k=q*8+j];
// B[k=8q+j][n=lane&15]. z reg (Mt,q,r) holds phys dim 32(Mt>>1)+8q+4(Mt&1)+r;
// center S-slot (c,Mt,q,r) == G k-slot 8q+4(Mt&1)+r of block Kt=Mt>>1.

#define STEPS 8
#define DTB   0.15f
#define EPSF  1e-4f

typedef short bf16x8 __attribute__((ext_vector_type(8)));
typedef float f32x4  __attribute__((ext_vector_type(4)));
typedef float f32x2  __attribute__((ext_vector_type(2)));
union FragU { int4 i; bf16x8 h; };

__device__ __forceinline__ f32x2 max2(f32x2 a, f32x2 b) {
    return __builtin_elementwise_max(a, b);
}
__device__ __forceinline__ f32x2 min2(f32x2 a, f32x2 b) {
    return __builtin_elementwise_min(a, b);
}

// byte-select pack: r = [lo.b2, lo.b3, hi.b2, hi.b3]  (one v_perm_b32)
__device__ __forceinline__ unsigned bfpt(float lo, float hi) { // trunc pack
    return __builtin_amdgcn_perm(__float_as_uint(hi), __float_as_uint(lo),
                                 0x07060302u);
}
__device__ __forceinline__ unsigned bfp(float lo, float hi) {  // round pack
    return __builtin_amdgcn_perm(__float_as_uint(hi) + 0x8000u,
                                 __float_as_uint(lo) + 0x8000u, 0x07060302u);
}

// d_ws layout:
//   int4 [0,    2048)  S-planes: ((c*4+Mt)*2+h)*64 + lane = bf16x8 of -2C[center][dims]
//   int4 [2048, 4096)  G-planes: ((Mt*4+c)*2+h)*64 + lane; row m16 -> perm dim
//                      D(Mt,m16); k-axis -> permuted centers cen(k)
//   f32  ws[16384..16640)  cn2[256]   (S-slot order: 64c+16Mt+4q+r)
//   f32  ws[16640..16896)  mu[256]
__global__ void pm_prep(const float* __restrict__ centers,
                        const float* __restrict__ mus,
                        unsigned* __restrict__ ws) {
    const int gtid = blockIdx.x * 256 + threadIdx.x;
    if (gtid < 2048) {                       // S-plane frags
        const int c = gtid >> 9, Mt = (gtid >> 7) & 3, h = (gtid >> 6) & 1;
        const int L = gtid & 63, m16 = L & 15, q = L >> 4;
        const float* row = centers + (size_t)(64 * c + 16 * Mt + m16) * 64 + 32 * h + 8 * q;
        uint4 u;
        u.x = bfp(-2.f * row[0], -2.f * row[1]);
        u.y = bfp(-2.f * row[2], -2.f * row[3]);
        u.z = bfp(-2.f * row[4], -2.f * row[5]);
        u.w = bfp(-2.f * row[6], -2.f * row[7]);
        ((uint4*)ws)[gtid] = u;
    } else if (gtid < 4096) {                // G-plane frags (permuted axes)
        const int i = gtid - 2048;
        const int Mt = i >> 9, c = (i >> 7) & 3, h = (i >> 6) & 1;
        const int L = i & 63, m16 = L & 15, q = L >> 4;
        const int dim = 32 * (Mt >> 1) + 8 * (m16 >> 2) + 4 * (Mt & 1) + (m16 & 3);
        const float* b0 = centers + (size_t)(64 * c + 32 * h + 4 * q) * 64 + dim;
        const float* b1 = b0 + 16 * 64;   // j=4..7 block (+16 centers)
        uint4 u;
        u.x = bfp(b0[0],   b0[64]);
        u.y = bfp(b0[128], b0[192]);
        u.z = bfp(b1[0],   b1[64]);
        u.w = bfp(b1[128], b1[192]);
        ((uint4*)ws)[gtid] = u;
    } else if (gtid < 4352) {                // cn2 / mu as f32 (S-slot order)
        const int t = gtid - 4096;
        const float* r = centers + (size_t)t * 64;
        float a0 = 0.f, a1 = 0.f, a2 = 0.f, a3 = 0.f;
#pragma unroll
        for (int d = 0; d < 64; d += 4) {
            a0 = fmaf(r[d],     r[d],     a0);
            a1 = fmaf(r[d + 1], r[d + 1], a1);
            a2 = fmaf(r[d + 2], r[d + 2], a2);
            a3 = fmaf(r[d + 3], r[d + 3], a3);
        }
        float c2 = (a0 + a1) + (a2 + a3);
        ((float*)ws)[16384 + t] = c2;
        ((float*)ws)[16640 + t] = mus[t];
    }
}

__global__ __launch_bounds__(512, 2)
void pm_main(const float* __restrict__ z_in,
             const unsigned* __restrict__ ws,
             float* __restrict__ z_out) {
    __shared__ int4 sG[2048];          // 32 KB: G-plane frags, block-shared

    const int4* wsA = (const int4*)ws;        // S-plane frags (L1/L2-resident)
    const int4* wsG = wsA + 2048;
    const float* wsC  = (const float*)ws + 16384;
    const float* wsMu = (const float*)ws + 16640;

    const int tid  = threadIdx.x;
    const int lane = tid & 63;
    const int w    = tid >> 6;         // wave 0..7
    const int m16  = lane & 15;
    const int q    = lane >> 4;

    // copy G planes to LDS (lane-linear, coalesced, conflict-free)
#pragma unroll
    for (int i = 0; i < 4; ++i) sG[i * 512 + tid] = wsG[i * 512 + tid];
    __syncthreads();

    const int pbase = blockIdx.x * 256 + w * 32;   // 256 particles/block, 32/wave

    // z state, permuted-dim layout: register (Mt,Nt,r) holds physical dim
    // 32(Mt>>1) + 8q + 4(Mt&1) + r for particle m16+16Nt (contig f32x4 load)
    f32x4 z[4][2];
#pragma unroll
    for (int Mt = 0; Mt < 4; ++Mt)
#pragma unroll
        for (int Nt = 0; Nt < 2; ++Nt)
            z[Mt][Nt] = *(const f32x4*)(z_in + (size_t)(pbase + m16 + 16 * Nt) * 64
                                        + 32 * (Mt >> 1) + 8 * q + 4 * (Mt & 1));

#pragma unroll 1
    for (int s = 0; s < STEPS; ++s) {
        // zz per particle (pk pairs + butterfly over q groups; perm-invariant)
        float zzp[2];
#pragma unroll
        for (int Nt = 0; Nt < 2; ++Nt) {
            f32x2 a2 = (f32x2){0.f, 0.f};
#pragma unroll
            for (int Mt = 0; Mt < 4; ++Mt) {
                f32x2 lo = (f32x2){z[Mt][Nt][0], z[Mt][Nt][1]};
                f32x2 hi = (f32x2){z[Mt][Nt][2], z[Mt][Nt][3]};
                a2 += lo * lo;
                a2 += hi * hi;
            }
            float a = a2.x + a2.y;
            a += __shfl_xor(a, 16, 64);
            a += __shfl_xor(a, 32, 64);
            zzp[Nt] = a;
        }

        // z -> B-frags: pure register pack (no LDS)
        FragU zf[2][2];
#pragma unroll
        for (int Kt = 0; Kt < 2; ++Kt)
#pragma unroll
            for (int Nt = 0; Nt < 2; ++Nt) {
                zf[Kt][Nt].i.x = (int)bfp(z[2 * Kt][Nt][0],     z[2 * Kt][Nt][1]);
                zf[Kt][Nt].i.y = (int)bfp(z[2 * Kt][Nt][2],     z[2 * Kt][Nt][3]);
                zf[Kt][Nt].i.z = (int)bfp(z[2 * Kt + 1][Nt][0], z[2 * Kt + 1][Nt][1]);
                zf[Kt][Nt].i.w = (int)bfp(z[2 * Kt + 1][Nt][2], z[2 * Kt + 1][Nt][3]);
            }

        f32x4 g[4][2];
#pragma unroll
        for (int Mt = 0; Mt < 4; ++Mt)
#pragma unroll
            for (int Nt = 0; Nt < 2; ++Nt) g[Mt][Nt] = (f32x4){0.f, 0.f, 0.f, 0.f};
        f32x2 nacc2a[2] = {(f32x2){0.f, 0.f}, (f32x2){0.f, 0.f}};
        f32x2 nacc2b[2] = {(f32x2){0.f, 0.f}, (f32x2){0.f, 0.f}};
        f32x2 swp2a[2]  = {(f32x2){0.f, 0.f}, (f32x2){0.f, 0.f}};
        f32x2 swp2b[2]  = {(f32x2){0.f, 0.f}, (f32x2){0.f, 0.f}};

#pragma unroll 2
        for (int c = 0; c < 4; ++c) {          // 4 chunks x 64 centers
            // S-phase, fused per Mt; w B-frags (wfB) built in-register;
            // sA frags from global (L1/L2) -- prefetched across the
            // back-edge by unroll 2 (proven R19)
            FragU wfB[2][2];
            const f32x2 eps2 = (f32x2){EPSF, EPSF};
#pragma unroll
            for (int Mt = 0; Mt < 4; ++Mt) {
                FragU a0, a1;
                a0.i = wsA[((c * 4 + Mt) * 2 + 0) * 64 + lane];
                a1.i = wsA[((c * 4 + Mt) * 2 + 1) * 64 + lane];
                const float4 cn4 = *(const float4*)(wsC  + 64 * c + 16 * Mt + 4 * q);
                const float4 mu4 = *(const float4*)(wsMu + 64 * c + 16 * Mt + 4 * q);
                const f32x2 cnlo = (f32x2){cn4.x, cn4.y}, cnhi = (f32x2){cn4.z, cn4.w};
                const f32x2 mulo = (f32x2){mu4.x, mu4.y}, muhi = (f32x2){mu4.z, mu4.w};
                f32x4 S[2];
#pragma unroll
                for (int Nt = 0; Nt < 2; ++Nt) {
                    const f32x2 zz2 = (f32x2){zzp[Nt], zzp[Nt]};
                    const f32x2 i0 = zz2 + cnlo, i1 = zz2 + cnhi;   // pk_add
                    f32x4 acc = (f32x4){i0.x, i0.y, i1.x, i1.y};
                    acc = __builtin_amdgcn_mfma_f32_16x16x32_bf16(a0.h, zf[0][Nt].h, acc, 0, 0, 0);
                    acc = __builtin_amdgcn_mfma_f32_16x16x32_bf16(a1.h, zf[1][Nt].h, acc, 0, 0, 0);
                    S[Nt] = acc;   // S = zz + |c|^2 - 2 z.c
                }

#pragma unroll
                for (int Nt = 0; Nt < 2; ++Nt) {
                    // packed elementwise: pairs (r0,r1) and (r2,r3)
                    f32x2 s0 = (f32x2){S[Nt][0], S[Nt][1]};
                    f32x2 s1 = (f32x2){S[Nt][2], S[Nt][3]};
                    f32x2 r20 = max2(s0, eps2);                 // == max(.,0)+eps here
                    f32x2 r21 = max2(s1, eps2);
                    f32x2 rin0, rin1;
                    rin0.x = __builtin_amdgcn_rsqf(r20.x);
                    rin0.y = __builtin_amdgcn_rsqf(r20.y);
                    rin1.x = __builtin_amdgcn_rsqf(r21.x);
                    rin1.y = __builtin_amdgcn_rsqf(r21.y);
                    f32x2 mur0 = mulo * rin0, mur1 = muhi * rin1;   // pk_mul
                    nacc2a[Nt] += mur0;                             // split chains (ILP)
                    nacc2b[Nt] += mur1;
                    f32x2 q0 = rin0 * rin0, q1 = rin1 * rin1;       // pk_mul
                    f32x2 wv0 = mur0 * q0,  wv1 = mur1 * q1;        // mu / r^3
                    swp2a[Nt] += wv0;                               // split chains (ILP)
                    swp2b[Nt] += wv1;
                    // w -> B-frag slot k=8q+4(Mt&1)+r of block Kt=Mt>>1
                    if ((Mt & 1) == 0) {
                        wfB[Mt >> 1][Nt].i.x = (int)bfpt(wv0.x, wv0.y);
                        wfB[Mt >> 1][Nt].i.y = (int)bfpt(wv1.x, wv1.y);
                    } else {
                        wfB[Mt >> 1][Nt].i.z = (int)bfpt(wv0.x, wv0.y);
                        wfB[Mt >> 1][Nt].i.w = (int)bfpt(wv1.x, wv1.y);
                    }
                }
            }

            // G-phase: ga frags from LDS (lane-linear, conflict-free);
            // wfB already in registers
#pragma unroll
            for (int Mt = 0; Mt < 4; ++Mt) {
                FragU ga0, ga1;
                ga0.i = sG[((Mt * 4 + c) * 2 + 0) * 64 + lane];
                ga1.i = sG[((Mt * 4 + c) * 2 + 1) * 64 + lane];
#pragma unroll
                for (int Nt = 0; Nt < 2; ++Nt) {
                    g[Mt][Nt] = __builtin_amdgcn_mfma_f32_16x16x32_bf16(ga0.h, wfB[0][Nt].h, g[Mt][Nt], 0, 0, 0);
                    g[Mt][Nt] = __builtin_amdgcn_mfma_f32_16x16x32_bf16(ga1.h, wfB[1][Nt].h, g[Mt][Nt], 0, 0, 0);
                }
            }
        }

        // reduce n, sw across q groups; packed z update
        float tco[2], swf[2];
#pragma unroll
        for (int Nt = 0; Nt < 2; ++Nt) {
            float a = (nacc2a[Nt].x + nacc2a[Nt].y) + (nacc2b[Nt].x + nacc2b[Nt].y);
            a += __shfl_xor(a, 16, 64);
            a += __shfl_xor(a, 32, 64);
            float b = (swp2a[Nt].x + swp2a[Nt].y) + (swp2b[Nt].x + swp2b[Nt].y);
            b += __shfl_xor(b, 16, 64);
            b += __shfl_xor(b, 32, 64);
            tco[Nt] = DTB * __builtin_amdgcn_rcpf(1.f + a);
            swf[Nt] = b;
        }
        const f32x2 lo2 = (f32x2){-3.f, -3.f}, hi2 = (f32x2){3.f, 3.f};
#pragma unroll
        for (int Mt = 0; Mt < 4; ++Mt)
#pragma unroll
            for (int Nt = 0; Nt < 2; ++Nt) {
                const f32x2 sw2 = (f32x2){swf[Nt], swf[Nt]};
                const f32x2 tc2 = (f32x2){tco[Nt], tco[Nt]};
#pragma unroll
                for (int p = 0; p < 2; ++p) {
                    f32x2 zp = (f32x2){z[Mt][Nt][2 * p], z[Mt][Nt][2 * p + 1]};
                    f32x2 gp = (f32x2){g[Mt][Nt][2 * p], g[Mt][Nt][2 * p + 1]};
                    f32x2 gd = gp - sw2 * zp;          // pk_fma
                    f32x2 zn = zp + tc2 * gd;          // pk_fma
                    zn = min2(max2(zn, lo2), hi2);     // pk_max + pk_min
                    z[Mt][Nt][2 * p]     = zn.x;
                    z[Mt][Nt][2 * p + 1] = zn.y;
                }
            }
    }

    // store: same permuted-dim contiguous f32x4 segments as the load
#pragma unroll
    for (int Mt = 0; Mt < 4; ++Mt)
#pragma unroll
        for (int Nt = 0; Nt < 2; ++Nt)
            *(f32x4*)(z_out + (size_t)(pbase + m16 + 16 * Nt) * 64
                      + 32 * (Mt >> 1) + 8 * q + 4 * (Mt & 1)) = z[Mt][Nt];
}

extern "C" void kernel_launch(void* const* d_in, const int* in_sizes, int n_in,
                              void* d_out, int out_size, void* d_ws, size_t ws_size,
                              hipStream_t stream) {
    const float* z       = (const float*)d_in[0];
    const float* centers = (const float*)d_in[1];
    const float* mus     = (const float*)d_in[2];
    float* out           = (float*)d_out;
    unsigned* ws         = (unsigned*)d_ws;

    pm_prep<<<dim3(17), dim3(256), 0, stream>>>(centers, mus, ws);
    // 131072 particles / 256 per block (8 waves x 32) = 512 blocks = 2/CU;
    // LDS 32KB x 2 = 64KB of 160KB -> both blocks trivially co-resident:
    // 16 waves/CU, 4 waves/SIMD
    pm_main<<<dim3(512), dim3(512), 0, stream>>>(z, ws, out);
}

// Round 20
// 189.676 us; speedup vs baseline: 1.0893x; 1.0831x over previous
//
#include <hip/hip_runtime.h>

// PMField R26: R23 (best, 138.5us) + s_setprio around MFMA clusters.
//  - R25 post-mortem: 32KB LDS left occ pinned at 22% (== R23's 64KB) ->
//    residency NOT LDS-limited; sA->L1 cost 10us. Both streams want the
//    LDS pipe (each single-32KB variant ~149; both-in-LDS 138.5). Reverted.
//  - Last untried knob matching this structure: s_setprio(1) around MFMA.
//    Catalog: pays only with wave phase-diversity (attn +4-7%, lockstep
//    GEMM 0%). Our waves are fully independent after the prologue barrier
//    (no loop barriers) -> the favorable regime. At ~2 waves/SIMD, biasing
//    the MFMA-entering wave lets matrix ops preempt the other wave's
//    VALU/LDS issue.
//  - If null/regress: R23 is final; structure converged (no pipe >56%,
//    all levers counter-tested).
//  - Body otherwise byte-identical to R23: 512-thr blocks, sA+sG 64KB LDS,
//    (512,2) (VGPR 80, proven safe), frag-dual register packing, permuted-
//    dim z layout, pk-f32 elementwise, acc-init fold, r2=fmax(S,EPS),
//    v_perm packs, f32 cn2/mu, chunk unroll 2, split accumulators.
// Layouts (HW-verified): C/D col=lane&15,row=q*4+r; A[m=lane&15][k=q*8+j];
// B[k=8q+j][n=lane&15]. z reg (Mt,q,r) holds phys dim 32(Mt>>1)+8q+4(Mt&1)+r;
// center S-slot (c,Mt,q,r) == G k-slot 8q+4(Mt&1)+r of block Kt=Mt>>1.

#define STEPS 8
#define DTB   0.15f
#define EPSF  1e-4f

typedef short bf16x8 __attribute__((ext_vector_type(8)));
typedef float f32x4  __attribute__((ext_vector_type(4)));
typedef float f32x2  __attribute__((ext_vector_type(2)));
union FragU { int4 i; bf16x8 h; };

__device__ __forceinline__ f32x2 max2(f32x2 a, f32x2 b) {
    return __builtin_elementwise_max(a, b);
}
__device__ __forceinline__ f32x2 min2(f32x2 a, f32x2 b) {
    return __builtin_elementwise_min(a, b);
}

// byte-select pack: r = [lo.b2, lo.b3, hi.b2, hi.b3]  (one v_perm_b32)
__device__ __forceinline__ unsigned bfpt(float lo, float hi) { // trunc pack
    return __builtin_amdgcn_perm(__float_as_uint(hi), __float_as_uint(lo),
                                 0x07060302u);
}
__device__ __forceinline__ unsigned bfp(float lo, float hi) {  // round pack
    return __builtin_amdgcn_perm(__float_as_uint(hi) + 0x8000u,
                                 __float_as_uint(lo) + 0x8000u, 0x07060302u);
}

// d_ws layout:
//   int4 [0,    2048)  S-planes: ((c*4+Mt)*2+h)*64 + lane = bf16x8 of -2C[center][dims]
//   int4 [2048, 4096)  G-planes: ((Mt*4+c)*2+h)*64 + lane; row m16 -> perm dim
//                      D(Mt,m16); k-axis -> permuted centers cen(k)
//   f32  ws[16384..16640)  cn2[256]   (S-slot order: 64c+16Mt+4q+r)
//   f32  ws[16640..16896)  mu[256]
__global__ void pm_prep(const float* __restrict__ centers,
                        const float* __restrict__ mus,
                        unsigned* __restrict__ ws) {
    const int gtid = blockIdx.x * 256 + threadIdx.x;
    if (gtid < 2048) {                       // S-plane frags
        const int c = gtid >> 9, Mt = (gtid >> 7) & 3, h = (gtid >> 6) & 1;
        const int L = gtid & 63, m16 = L & 15, q = L >> 4;
        const float* row = centers + (size_t)(64 * c + 16 * Mt + m16) * 64 + 32 * h + 8 * q;
        uint4 u;
        u.x = bfp(-2.f * row[0], -2.f * row[1]);
        u.y = bfp(-2.f * row[2], -2.f * row[3]);
        u.z = bfp(-2.f * row[4], -2.f * row[5]);
        u.w = bfp(-2.f * row[6], -2.f * row[7]);
        ((uint4*)ws)[gtid] = u;
    } else if (gtid < 4096) {                // G-plane frags (permuted axes)
        const int i = gtid - 2048;
        const int Mt = i >> 9, c = (i >> 7) & 3, h = (i >> 6) & 1;
        const int L = i & 63, m16 = L & 15, q = L >> 4;
        const int dim = 32 * (Mt >> 1) + 8 * (m16 >> 2) + 4 * (Mt & 1) + (m16 & 3);
        const float* b0 = centers + (size_t)(64 * c + 32 * h + 4 * q) * 64 + dim;
        const float* b1 = b0 + 16 * 64;   // j=4..7 block (+16 centers)
        uint4 u;
        u.x = bfp(b0[0],   b0[64]);
        u.y = bfp(b0[128], b0[192]);
        u.z = bfp(b1[0],   b1[64]);
        u.w = bfp(b1[128], b1[192]);
        ((uint4*)ws)[gtid] = u;
    } else if (gtid < 4352) {                // cn2 / mu as f32 (S-slot order)
        const int t = gtid - 4096;
        const float* r = centers + (size_t)t * 64;
        float a0 = 0.f, a1 = 0.f, a2 = 0.f, a3 = 0.f;
#pragma unroll
        for (int d = 0; d < 64; d += 4) {
            a0 = fmaf(r[d],     r[d],     a0);
            a1 = fmaf(r[d + 1], r[d + 1], a1);
            a2 = fmaf(r[d + 2], r[d + 2], a2);
            a3 = fmaf(r[d + 3], r[d + 3], a3);
        }
        float c2 = (a0 + a1) + (a2 + a3);
        ((float*)ws)[16384 + t] = c2;
        ((float*)ws)[16640 + t] = mus[t];
    }
}

__global__ __launch_bounds__(512, 2)
void pm_main(const float* __restrict__ z_in,
             const unsigned* __restrict__ ws,
             float* __restrict__ z_out) {
    __shared__ int4 sA[2048];          // 32 KB: S-plane frags, block-shared
    __shared__ int4 sG[2048];          // 32 KB: G-plane frags, block-shared

    const int4* wsA = (const int4*)ws;
    const int4* wsG = wsA + 2048;
    const float* wsC  = (const float*)ws + 16384;
    const float* wsMu = (const float*)ws + 16640;

    const int tid  = threadIdx.x;
    const int lane = tid & 63;
    const int w    = tid >> 6;         // wave 0..7
    const int m16  = lane & 15;
    const int q    = lane >> 4;

    // copy S+G planes to LDS (lane-linear, coalesced, conflict-free)
#pragma unroll
    for (int i = 0; i < 4; ++i) sA[i * 512 + tid] = wsA[i * 512 + tid];
#pragma unroll
    for (int i = 0; i < 4; ++i) sG[i * 512 + tid] = wsG[i * 512 + tid];
    __syncthreads();

    const int pbase = blockIdx.x * 256 + w * 32;   // 256 particles/block, 32/wave

    // z state, permuted-dim layout: register (Mt,Nt,r) holds physical dim
    // 32(Mt>>1) + 8q + 4(Mt&1) + r for particle m16+16Nt (contig f32x4 load)
    f32x4 z[4][2];
#pragma unroll
    for (int Mt = 0; Mt < 4; ++Mt)
#pragma unroll
        for (int Nt = 0; Nt < 2; ++Nt)
            z[Mt][Nt] = *(const f32x4*)(z_in + (size_t)(pbase + m16 + 16 * Nt) * 64
                                        + 32 * (Mt >> 1) + 8 * q + 4 * (Mt & 1));

#pragma unroll 1
    for (int s = 0; s < STEPS; ++s) {
        // zz per particle (pk pairs + butterfly over q groups; perm-invariant)
        float zzp[2];
#pragma unroll
        for (int Nt = 0; Nt < 2; ++Nt) {
            f32x2 a2 = (f32x2){0.f, 0.f};
#pragma unroll
            for (int Mt = 0; Mt < 4; ++Mt) {
                f32x2 lo = (f32x2){z[Mt][Nt][0], z[Mt][Nt][1]};
                f32x2 hi = (f32x2){z[Mt][Nt][2], z[Mt][Nt][3]};
                a2 += lo * lo;
                a2 += hi * hi;
            }
            float a = a2.x + a2.y;
            a += __shfl_xor(a, 16, 64);
            a += __shfl_xor(a, 32, 64);
            zzp[Nt] = a;
        }

        // z -> B-frags: pure register pack (no LDS)
        FragU zf[2][2];
#pragma unroll
        for (int Kt = 0; Kt < 2; ++Kt)
#pragma unroll
            for (int Nt = 0; Nt < 2; ++Nt) {
                zf[Kt][Nt].i.x = (int)bfp(z[2 * Kt][Nt][0],     z[2 * Kt][Nt][1]);
                zf[Kt][Nt].i.y = (int)bfp(z[2 * Kt][Nt][2],     z[2 * Kt][Nt][3]);
                zf[Kt][Nt].i.z = (int)bfp(z[2 * Kt + 1][Nt][0], z[2 * Kt + 1][Nt][1]);
                zf[Kt][Nt].i.w = (int)bfp(z[2 * Kt + 1][Nt][2], z[2 * Kt + 1][Nt][3]);
            }

        f32x4 g[4][2];
#pragma unroll
        for (int Mt = 0; Mt < 4; ++Mt)
#pragma unroll
            for (int Nt = 0; Nt < 2; ++Nt) g[Mt][Nt] = (f32x4){0.f, 0.f, 0.f, 0.f};
        f32x2 nacc2a[2] = {(f32x2){0.f, 0.f}, (f32x2){0.f, 0.f}};
        f32x2 nacc2b[2] = {(f32x2){0.f, 0.f}, (f32x2){0.f, 0.f}};
        f32x2 swp2a[2]  = {(f32x2){0.f, 0.f}, (f32x2){0.f, 0.f}};
        f32x2 swp2b[2]  = {(f32x2){0.f, 0.f}, (f32x2){0.f, 0.f}};

#pragma unroll 2
        for (int c = 0; c < 4; ++c) {          // 4 chunks x 64 centers
            // S-phase, fused per Mt; w B-frags (wfB) built in-register
            FragU wfB[2][2];
            const f32x2 eps2 = (f32x2){EPSF, EPSF};
#pragma unroll
            for (int Mt = 0; Mt < 4; ++Mt) {
                FragU a0, a1;
                a0.i = sA[((c * 4 + Mt) * 2 + 0) * 64 + lane];
                a1.i = sA[((c * 4 + Mt) * 2 + 1) * 64 + lane];
                const float4 cn4 = *(const float4*)(wsC  + 64 * c + 16 * Mt + 4 * q);
                const float4 mu4 = *(const float4*)(wsMu + 64 * c + 16 * Mt + 4 * q);
                const f32x2 cnlo = (f32x2){cn4.x, cn4.y}, cnhi = (f32x2){cn4.z, cn4.w};
                const f32x2 mulo = (f32x2){mu4.x, mu4.y}, muhi = (f32x2){mu4.z, mu4.w};
                f32x4 S[2];
                __builtin_amdgcn_s_setprio(1);           // favor MFMA-entering wave
#pragma unroll
                for (int Nt = 0; Nt < 2; ++Nt) {
                    const f32x2 zz2 = (f32x2){zzp[Nt], zzp[Nt]};
                    const f32x2 i0 = zz2 + cnlo, i1 = zz2 + cnhi;   // pk_add
                    f32x4 acc = (f32x4){i0.x, i0.y, i1.x, i1.y};
                    acc = __builtin_amdgcn_mfma_f32_16x16x32_bf16(a0.h, zf[0][Nt].h, acc, 0, 0, 0);
                    acc = __builtin_amdgcn_mfma_f32_16x16x32_bf16(a1.h, zf[1][Nt].h, acc, 0, 0, 0);
                    S[Nt] = acc;   // S = zz + |c|^2 - 2 z.c
                }
                __builtin_amdgcn_s_setprio(0);

#pragma unroll
                for (int Nt = 0; Nt < 2; ++Nt) {
                    // packed elementwise: pairs (r0,r1) and (r2,r3)
                    f32x2 s0 = (f32x2){S[Nt][0], S[Nt][1]};
                    f32x2 s1 = (f32x2){S[Nt][2], S[Nt][3]};
                    f32x2 r20 = max2(s0, eps2);                 // == max(.,0)+eps here
                    f32x2 r21 = max2(s1, eps2);
                    f32x2 rin0, rin1;
                    rin0.x = __builtin_amdgcn_rsqf(r20.x);
                    rin0.y = __builtin_amdgcn_rsqf(r20.y);
                    rin1.x = __builtin_amdgcn_rsqf(r21.x);
                    rin1.y = __builtin_amdgcn_rsqf(r21.y);
                    f32x2 mur0 = mulo * rin0, mur1 = muhi * rin1;   // pk_mul
                    nacc2a[Nt] += mur0;                             // split chains (ILP)
                    nacc2b[Nt] += mur1;
                    f32x2 q0 = rin0 * rin0, q1 = rin1 * rin1;       // pk_mul
                    f32x2 wv0 = mur0 * q0,  wv1 = mur1 * q1;        // mu / r^3
                    swp2a[Nt] += wv0;                               // split chains (ILP)
                    swp2b[Nt] += wv1;
                    // w -> B-frag slot k=8q+4(Mt&1)+r of block Kt=Mt>>1
                    if ((Mt & 1) == 0) {
                        wfB[Mt >> 1][Nt].i.x = (int)bfpt(wv0.x, wv0.y);
                        wfB[Mt >> 1][Nt].i.y = (int)bfpt(wv1.x, wv1.y);
                    } else {
                        wfB[Mt >> 1][Nt].i.z = (int)bfpt(wv0.x, wv0.y);
                        wfB[Mt >> 1][Nt].i.w = (int)bfpt(wv1.x, wv1.y);
                    }
                }
            }

            // G-phase: ga frags from LDS (lane-linear, conflict-free);
            // wfB already in registers
#pragma unroll
            for (int Mt = 0; Mt < 4; ++Mt) {
                FragU ga0, ga1;
                ga0.i = sG[((Mt * 4 + c) * 2 + 0) * 64 + lane];
                ga1.i = sG[((Mt * 4 + c) * 2 + 1) * 64 + lane];
                __builtin_amdgcn_s_setprio(1);       // favor MFMA-entering wave
#pragma unroll
                for (int Nt = 0; Nt < 2; ++Nt) {
                    g[Mt][Nt] = __builtin_amdgcn_mfma_f32_16x16x32_bf16(ga0.h, wfB[0][Nt].h, g[Mt][Nt], 0, 0, 0);
                    g[Mt][Nt] = __builtin_amdgcn_mfma_f32_16x16x32_bf16(ga1.h, wfB[1][Nt].h, g[Mt][Nt], 0, 0, 0);
                }
                __builtin_amdgcn_s_setprio(0);
            }
        }

        // reduce n, sw across q groups; packed z update
        float tco[2], swf[2];
#pragma unroll
        for (int Nt = 0; Nt < 2; ++Nt) {
            float a = (nacc2a[Nt].x + nacc2a[Nt].y) + (nacc2b[Nt].x + nacc2b[Nt].y);
            a += __shfl_xor(a, 16, 64);
            a += __shfl_xor(a, 32, 64);
            float b = (swp2a[Nt].x + swp2a[Nt].y) + (swp2b[Nt].x + swp2b[Nt].y);
            b += __shfl_xor(b, 16, 64);
            b += __shfl_xor(b, 32, 64);
            tco[Nt] = DTB * __builtin_amdgcn_rcpf(1.f + a);
            swf[Nt] = b;
        }
        const f32x2 lo2 = (f32x2){-3.f, -3.f}, hi2 = (f32x2){3.f, 3.f};
#pragma unroll
        for (int Mt = 0; Mt < 4; ++Mt)
#pragma unroll
            for (int Nt = 0; Nt < 2; ++Nt) {
                const f32x2 sw2 = (f32x2){swf[Nt], swf[Nt]};
                const f32x2 tc2 = (f32x2){tco[Nt], tco[Nt]};
#pragma unroll
                for (int p = 0; p < 2; ++p) {
                    f32x2 zp = (f32x2){z[Mt][Nt][2 * p], z[Mt][Nt][2 * p + 1]};
                    f32x2 gp = (f32x2){g[Mt][Nt][2 * p], g[Mt][Nt][2 * p + 1]};
                    f32x2 gd = gp - sw2 * zp;          // pk_fma
                    f32x2 zn = zp + tc2 * gd;          // pk_fma
                    zn = min2(max2(zn, lo2), hi2);     // pk_max + pk_min
                    z[Mt][Nt][2 * p]     = zn.x;
                    z[Mt][Nt][2 * p + 1] = zn.y;
                }
            }
    }

    // store: same permuted-dim contiguous f32x4 segments as the load
#pragma unroll
    for (int Mt = 0; Mt < 4; ++Mt)
#pragma unroll
        for (int Nt = 0; Nt < 2; ++Nt)
            *(f32x4*)(z_out + (size_t)(pbase + m16 + 16 * Nt) * 64
                      + 32 * (Mt >> 1) + 8 * q + 4 * (Mt & 1)) = z[Mt][Nt];
}

extern "C" void kernel_launch(void* const* d_in, const int* in_sizes, int n_in,
                              void* d_out, int out_size, void* d_ws, size_t ws_size,
                              hipStream_t stream) {
    const float* z       = (const float*)d_in[0];
    const float* centers = (const float*)d_in[1];
    const float* mus     = (const float*)d_in[2];
    float* out           = (float*)d_out;
    unsigned* ws         = (unsigned*)d_ws;

    pm_prep<<<dim3(17), dim3(256), 0, stream>>>(centers, mus, ws);
    // 131072 particles / 256 per block (8 waves x 32) = 512 blocks = 2/CU
    pm_main<<<dim3(512), dim3(512), 0, stream>>>(z, ws, out);
}